// Round 2
// baseline (302.193 us; speedup 1.0000x reference)
//
#include <hip/hip_runtime.h>
#include <hip/hip_bf16.h>

#define RD 64
#define UD 64
#define VD 64
#define HD 128
#define XD 64
#define NB 8
#define SITES 1024

typedef float f32x4 __attribute__((ext_vector_type(4)));
typedef float f32x2 __attribute__((ext_vector_type(2)));
typedef __bf16 bf16x4 __attribute__((ext_vector_type(4)));
typedef __bf16 bf16x8 __attribute__((ext_vector_type(8)));
typedef unsigned int u32x4 __attribute__((ext_vector_type(4)));
typedef unsigned short u16;
typedef unsigned short u16x4 __attribute__((ext_vector_type(4)));

// Raw workgroup barrier WITHOUT the vmcnt(0) drain __syncthreads carries.
// 0xC07F = lgkmcnt(0), vmcnt=63 (open), expcnt=7 (open) on gfx9-lineage.
__device__ __forceinline__ void lds_barrier() {
  __builtin_amdgcn_s_waitcnt(0xC07F);
  __builtin_amdgcn_s_barrier();
}

// ---------------- kprep: all three input transforms in one launch ----------------
// b < 256   : w2 [x][r][h] fp32 -> w2t bf16 [r][x][h]
// b < 384   : r  [n][s][r] fp32 -> rt fp32 [n][r][s]
// else      : u  [n][r][u][v] fp32 -> ut fp32 [r][u][v][n]   (2048 blocks)
__global__ void kprep(const float* __restrict__ w2, u16* __restrict__ w2t,
                      const float* __restrict__ r, float* __restrict__ rt,
                      const float* __restrict__ u, float* __restrict__ ut) {
  __shared__ float tl[64][68];
  int b = blockIdx.x;
  int t = threadIdx.x;
  if (b < 256) {
    int rr = b >> 2, qq = b & 3;
    for (int i = 0; i < 8; ++i) {
      int idx = qq * 2048 + i * 256 + t;   // (x,h)
      int x = idx >> 7, h = idx & 127;
      float val = w2[((size_t)x * RD + rr) * HD + h];
      __hip_bfloat16 hv = __float2bfloat16(val);
      w2t[((size_t)rr * XD + x) * HD + h] = *(u16*)&hv;
    }
  } else if (b < 384) {
    int bb = b - 256;
    int n = bb >> 4, sb = (bb & 15) * 64;
    for (int i = 0; i < 4; ++i) {
      int flat = i * 256 + t;
      int s = flat >> 4, ch = flat & 15;
      f32x4 d = *(const f32x4*)(r + ((size_t)(n * SITES + sb + s) * RD + ch * 4));
      *(f32x4*)&tl[s][ch * 4] = d;
    }
    __syncthreads();
    for (int i = 0; i < 4; ++i) {
      int flat = i * 256 + t;
      int rr = flat >> 4, ch = flat & 15;
      f32x4 o;
      o.x = tl[ch * 4 + 0][rr];
      o.y = tl[ch * 4 + 1][rr];
      o.z = tl[ch * 4 + 2][rr];
      o.w = tl[ch * 4 + 3][rr];
      *(f32x4*)(rt + ((size_t)(n * RD + rr) * SITES + sb + ch * 4)) = o;
    }
  } else {
    int f = (b - 384) * 256 + t;        // 524288 f32x4 units of ut
    int nh = f & 1, v = (f >> 1) & 63, uu = (f >> 7) & 63, rr = f >> 13;
    f32x4 o;
#pragma unroll
    for (int k = 0; k < 4; ++k)
      o[k] = u[(((size_t)(nh * 4 + k) * RD + rr) * UD + uu) * VD + v];
    *(f32x4*)(ut + (size_t)f * 4) = o;
  }
}

// ---------------- k_a_full v2: latency-fixed full-u contraction -----------------
// R1 version was grid-512/256thr = 8 waves/CU with ~12 loads in flight ->
// ~1.5-4 KB/CU outstanding vs the ~9.2 KB Little's-law requirement (10.25 B/cyc
// x ~900 cyc HBM latency) -> latency-bound on the 134 MB w1 stream.
// v2: 256 blocks x 1024 threads (exactly 1 block/CU, 16 waves/CU).  n is split
// across the 4 wave-groups (acc[2][8] per thread, 16 VGPR), which widens the
// per-thread w1 load to 32 B contiguous.  PF=4 software-pipeline ring (fully
// unrolled -> static buffer indices) keeps 12 loads/wave in flight; 4 n-groups
// share the same w1 lines (L1 absorbs re-reads).  Numerics identical: same
// sequential fp32 u-sum per (v,h), single bf16 round at the end.
#define PF 4
__global__ __launch_bounds__(1024, 4) void k_a_full(const float* __restrict__ w1,
                                                    const float* __restrict__ ut,
                                                    u16* __restrict__ at) {
  // tile[n][h_local][v_local] f32, row stride 40 (160 B: 16 B-aligned f32x4 reads)
  __shared__ float tile[8 * 64 * 40];   // 80 KB
  int b = blockIdx.x;                   // 256 = rr(64) x vh(2) x hb(2)
  int rr = b >> 2, vh = (b >> 1) & 1, hb = b & 1;
  int t = threadIdx.x;
  int ng = t >> 8;                      // n-group (4): n0 = ng*2
  int L = t & 255;
  int vl = L >> 3, hs = L & 7;          // v-local (32), h-strip (8 h each)
  int v = vh * 32 + vl;
  int h0 = hb * 64 + hs * 8;
  int n0 = ng * 2;
  const float* w1p = w1 + (((size_t)rr * UD) * VD + v) * HD + h0;
  const float* up  = ut + (((size_t)rr * UD) * VD + v) * NB + n0;
  const size_t wstep = (size_t)VD * HD;   // floats per uu in w1
  const size_t ustep = (size_t)VD * NB;   // floats per uu in ut

  float acc[2][8];
#pragma unroll
  for (int nn = 0; nn < 2; ++nn)
#pragma unroll
    for (int j = 0; j < 8; ++j) acc[nn][j] = 0.f;

  // prefetch ring
  f32x4 wa[PF], wb[PF];
  f32x2 ub[PF];
#pragma unroll
  for (int p = 0; p < PF; ++p) {
    wa[p] = *(const f32x4*)(w1p + (size_t)p * wstep);
    wb[p] = *(const f32x4*)(w1p + (size_t)p * wstep + 4);
    ub[p] = *(const f32x2*)(up + (size_t)p * ustep);
  }
#pragma unroll
  for (int uu = 0; uu < 64; ++uu) {
    const int p = uu & (PF - 1);
    f32x4 w0 = wa[p];
    f32x4 w1v = wb[p];
    f32x2 uv = ub[p];
    if (uu + PF < 64) {
      wa[p] = *(const f32x4*)(w1p + (size_t)(uu + PF) * wstep);
      wb[p] = *(const f32x4*)(w1p + (size_t)(uu + PF) * wstep + 4);
      ub[p] = *(const f32x2*)(up + (size_t)(uu + PF) * ustep);
    }
#pragma unroll
    for (int j = 0; j < 4; ++j) {
      acc[0][j]     += uv.x * w0[j];
      acc[0][j + 4] += uv.x * w1v[j];
      acc[1][j]     += uv.y * w0[j];
      acc[1][j + 4] += uv.y * w1v[j];
    }
  }

  // epilogue: one 80 KB LDS transpose (all 8 n at once), then bf16 stores along v
#pragma unroll
  for (int nn = 0; nn < 2; ++nn)
#pragma unroll
    for (int j = 0; j < 8; ++j)
      tile[((n0 + nn) * 64 + hs * 8 + j) * 40 + vl] = acc[nn][j];
  __syncthreads();
  // 4096 f32x4 units: (n(8), hl(64), vs(8)) ; 4 per thread
#pragma unroll
  for (int k = 0; k < 4; ++k) {
    int uidx = k * 1024 + t;
    int n = uidx >> 9, hl = (uidx >> 3) & 63, vs = uidx & 7;
    f32x4 blk = *(const f32x4*)&tile[(n * 64 + hl) * 40 + vs * 4];
    u16x4 o;
#pragma unroll
    for (int j = 0; j < 4; ++j) {
      __hip_bfloat16 hv = __float2bfloat16(blk[j]);
      o[j] = *(u16*)&hv;
    }
    *(u16x4*)(at + ((size_t)(n * RD + rr) * HD + hb * 64 + hl) * VD + vh * 32 + vs * 4) = o;
  }
}

// ---------------- k_main: fused GEMM1 (P^T = A_r^T * V^T) + relu*r + GEMM2 ------
// R6 known-good structure (512 blocks x 256 thr, 64 KB double-buffered swizzled
// Plds, ONE lds_barrier per rr).  Unchanged.
__global__ __launch_bounds__(256, 1) void k_main(const float* __restrict__ vin,
                                                 const u16* __restrict__ at,
                                                 const u16* __restrict__ w2t,
                                                 const float* __restrict__ rt,
                                                 float* __restrict__ pbuf) {
  __shared__ __align__(16) char Plds[2 * 128 * 256];   // 64 KB exactly
  int b = blockIdx.x;                 // 512 = n(8) x stile(8) x rchunk(8)
  int rc = b & 7, st = (b >> 3) & 7, n = b >> 6;
  int t = threadIdx.x;
  int w = t >> 6, L = t & 63, q = L >> 4, c = L & 15;
  int g2m = w >> 1, g2x = w & 1;      // GEMM2: s-half x x-half

  // V fragments (B-operand of GEMM1), register-resident for all r-steps
  bf16x8 vf[4][2];
#pragma unroll
  for (int nt = 0; nt < 4; ++nt)
#pragma unroll
    for (int ks = 0; ks < 2; ++ks) {
      int s = (w & 1) * 64 + nt * 16 + c;
      const float* vp = vin + ((size_t)(n * SITES + st * 128 + s) * VD + ks * 32 + q * 8);
      f32x4 a0 = *(const f32x4*)vp;
      f32x4 a1 = *(const f32x4*)(vp + 4);
      bf16x8 f;
      f[0] = (__bf16)a0.x; f[1] = (__bf16)a0.y; f[2] = (__bf16)a0.z; f[3] = (__bf16)a0.w;
      f[4] = (__bf16)a1.x; f[5] = (__bf16)a1.y; f[6] = (__bf16)a1.z; f[7] = (__bf16)a1.w;
      vf[nt][ks] = f;
    }

  f32x4 o[4][2];
#pragma unroll
  for (int i = 0; i < 4; i++)
#pragma unroll
    for (int j = 0; j < 2; j++) o[i][j] = (f32x4)0.f;

  int g1m = w >> 1, g1n = w & 1;      // GEMM1: h-half x s-half
  for (int rr = rc * 8; rr < rc * 8 + 8; ++rr) {
    const u16* abase = at + (size_t)(n * RD + rr) * 8192;   // [h][v] plain

    // A-frags direct from global: 16B = 8 consecutive v at fixed h
    bf16x8 af[4][2];
#pragma unroll
    for (int mt = 0; mt < 4; ++mt)
#pragma unroll
      for (int ks = 0; ks < 2; ++ks) {
        int h = g1m * 64 + mt * 16 + c;
        int vb = ks * 4 + q;
        af[mt][ks] = *(const bf16x8*)(abase + (size_t)h * VD + vb * 8);
      }
    // W2r b-frags from global (L2-hot)
    u32x4 wraw[2][4];
#pragma unroll
    for (int xt = 0; xt < 2; ++xt)
#pragma unroll
      for (int k2 = 0; k2 < 4; ++k2) {
        int xg = g2x * 32 + xt * 16 + c;
        wraw[xt][k2] = *(const u32x4*)((const char*)w2t +
                        (((size_t)(rr * XD + xg)) * HD + k2 * 32 + q * 8) * 2);
      }
    float rsc[4];
#pragma unroll
    for (int nt = 0; nt < 4; ++nt)
      rsc[nt] = rt[(size_t)(n * RD + rr) * SITES + st * 128 + g1n * 64 + nt * 16 + c];

    // GEMM1: D = A_r^T (m=h) x V^T (n=s), K=v=64
    f32x4 cc[4][4];
#pragma unroll
    for (int mt = 0; mt < 4; ++mt)
#pragma unroll
      for (int nt = 0; nt < 4; ++nt) cc[mt][nt] = (f32x4)0.f;
#pragma unroll
    for (int ks = 0; ks < 2; ++ks)
#pragma unroll
      for (int mt = 0; mt < 4; ++mt)
#pragma unroll
        for (int nt = 0; nt < 4; ++nt)
          cc[mt][nt] = __builtin_amdgcn_mfma_f32_16x16x32_bf16(af[mt][ks], vf[nt][ks],
                                                               cc[mt][nt], 0, 0, 0);

    // relu, scale by r, pack to Plds buf rr&1, XOR-swizzled 16B blocks:
    // element (s, h-block hb8=h>>3) stored at block (hb8 ^ (s&15)) within row s.
    char* PB = Plds + (rr & 1) * 32768;
#pragma unroll
    for (int mt = 0; mt < 4; ++mt)
#pragma unroll
      for (int nt = 0; nt < 4; ++nt) {
        float sc = rsc[nt];
        bf16x4 pv;
#pragma unroll
        for (int jj = 0; jj < 4; ++jj) {
          float x = cc[mt][nt][jj];
          x = x > 0.f ? x : 0.f;
          pv[jj] = (__bf16)(x * sc);
        }
        int s = g1n * 64 + nt * 16 + c;          // s&15 == c
        int blk = g1m * 8 + mt * 2 + (q >> 1);   // = h>>3
        *(bf16x4*)(PB + (size_t)s * 256 + (size_t)((blk ^ c) * 16 + (q & 1) * 8)) = pv;
      }
    lds_barrier();   // lgkm-only barrier — no vmcnt(0) drain per rr

    // GEMM2: O[s,x] += P (m=s, A-op) x W2r^T (n=x), K=h=128
#pragma unroll
    for (int k2 = 0; k2 < 4; ++k2) {
      bf16x8 wf0 = __builtin_bit_cast(bf16x8, wraw[0][k2]);
      bf16x8 wf1 = __builtin_bit_cast(bf16x8, wraw[1][k2]);
#pragma unroll
      for (int mt = 0; mt < 4; ++mt) {
        int s = g2m * 64 + mt * 16 + c;          // s&15 == c
        int blk = k2 * 4 + q;                    // = h>>3
        bf16x8 pf = *(const bf16x8*)(PB + (size_t)s * 256 + (size_t)((blk ^ c) * 16));
        o[mt][0] = __builtin_amdgcn_mfma_f32_16x16x32_bf16(pf, wf0, o[mt][0], 0, 0, 0);
        o[mt][1] = __builtin_amdgcn_mfma_f32_16x16x32_bf16(pf, wf1, o[mt][1], 0, 0, 0);
      }
    }
  }
  // epilogue: plain vector stores to partial buffer pbuf[rc][n][st][x][s]
#pragma unroll
  for (int mt = 0; mt < 4; ++mt)
#pragma unroll
    for (int xt = 0; xt < 2; ++xt) {
      int s0 = g2m * 64 + mt * 16 + q * 4;
      int x = g2x * 32 + xt * 16 + c;
      size_t off = ((((size_t)rc * NB + n) * 8 + st) * XD + x) * 128 + s0;
      *(f32x4*)(pbuf + off) = o[mt][xt];
    }
}

// ---------------- k_reduce: out[n][s][x] = sum_rc pbuf[rc][n][st][x][s] ---------
__global__ __launch_bounds__(256) void k_reduce(const float* __restrict__ pbuf,
                                                float* __restrict__ out) {
  __shared__ float tile[128][17];
  int b = blockIdx.x;                 // 256 = n(8) x st(8) x xq(4)
  int n = b >> 5, st = (b >> 2) & 7, xq = b & 3;
  int t = threadIdx.x;
  int sq = t & 31, xl = t >> 5;       // phase-1: s-quad, x-lane (8)
#pragma unroll
  for (int p = 0; p < 2; ++p) {
    int x = xq * 16 + p * 8 + xl;
    f32x4 sum = (f32x4)0.f;
#pragma unroll
    for (int rcc = 0; rcc < 8; ++rcc) {
      size_t off = ((((size_t)rcc * NB + n) * 8 + st) * XD + x) * 128 + sq * 4;
      f32x4 d = *(const f32x4*)(pbuf + off);
      sum.x += d.x; sum.y += d.y; sum.z += d.z; sum.w += d.w;
    }
#pragma unroll
    for (int k = 0; k < 4; ++k) tile[sq * 4 + k][p * 8 + xl] = sum[k];
  }
  __syncthreads();
  // phase-2: coalesced out write, f32x4 along x
#pragma unroll
  for (int k = 0; k < 2; ++k) {
    int flat = k * 256 + t;
    int s = flat >> 2, c4 = flat & 3;
    f32x4 o;
#pragma unroll
    for (int j = 0; j < 4; ++j) o[j] = tile[s][c4 * 4 + j];
    *(f32x4*)(out + ((size_t)(n * SITES + st * 128 + s) * XD + xq * 16 + c4 * 4)) = o;
  }
}

extern "C" void kernel_launch(void* const* d_in, const int* in_sizes, int n_in,
                              void* d_out, int out_size, void* d_ws, size_t ws_size,
                              hipStream_t stream) {
  const float* r  = (const float*)d_in[0];
  const float* u  = (const float*)d_in[1];
  const float* v  = (const float*)d_in[2];
  const float* w1 = (const float*)d_in[3];
  const float* w2 = (const float*)d_in[4];
  float* out = (float*)d_out;
  char* ws = (char*)d_ws;
  u16* at     = (u16*)(ws);                         // 8 MB  bf16 a, [n][r][h][v]
  u16* w2t    = (u16*)(ws + ((size_t)8 << 20));     // 1 MB  bf16 w2 [r][x][h]
  float* rt   = (float*)(ws + ((size_t)9 << 20));   // 2 MB  fp32 r [n][r][s]
  float* ut   = (float*)(ws + ((size_t)11 << 20));  // 8 MB  fp32 u [r][u][v][n]
  float* pbuf = (float*)(ws + ((size_t)19 << 20));  // 16 MB fp32 out-partials [rc][n][st][x][s]

  hipLaunchKernelGGL(kprep, dim3(2432), dim3(256), 0, stream, w2, w2t, r, rt, u, ut);
  hipLaunchKernelGGL(k_a_full, dim3(256), dim3(1024), 0, stream, w1, ut, at);
  hipLaunchKernelGGL(k_main, dim3(512), dim3(256), 0, stream, v, at, w2t, rt, pbuf);
  hipLaunchKernelGGL(k_reduce, dim3(256), dim3(256), 0, stream, pbuf, out);
}

// Round 3
// 255.292 us; speedup vs baseline: 1.1837x; 1.1837x over previous
//
#include <hip/hip_runtime.h>
#include <hip/hip_bf16.h>

#define RD 64
#define UD 64
#define VD 64
#define HD 128
#define XD 64
#define NB 8
#define SITES 1024

typedef float f32x4 __attribute__((ext_vector_type(4)));
typedef float f32x2 __attribute__((ext_vector_type(2)));
typedef __bf16 bf16x4 __attribute__((ext_vector_type(4)));
typedef __bf16 bf16x8 __attribute__((ext_vector_type(8)));
typedef unsigned int u32x4 __attribute__((ext_vector_type(4)));
typedef unsigned short u16;
typedef unsigned short u16x4 __attribute__((ext_vector_type(4)));

// Raw workgroup barrier WITHOUT the vmcnt(0) drain __syncthreads carries.
// 0xC07F = lgkmcnt(0), vmcnt=63 (open), expcnt=7 (open) on gfx9-lineage.
__device__ __forceinline__ void lds_barrier() {
  __builtin_amdgcn_s_waitcnt(0xC07F);
  __builtin_amdgcn_s_barrier();
}

// ---------------- kprep: all three input transforms in one launch ----------------
// b < 256   : w2 [x][r][h] fp32 -> w2t bf16 [r][x][h]
// b < 384   : r  [n][s][r] fp32 -> rt fp32 [n][r][s]
// else      : u  [n][r][u][v] fp32 -> ut fp32 [r][u][v][n]   (2048 blocks)
__global__ void kprep(const float* __restrict__ w2, u16* __restrict__ w2t,
                      const float* __restrict__ r, float* __restrict__ rt,
                      const float* __restrict__ u, float* __restrict__ ut) {
  __shared__ float tl[64][68];
  int b = blockIdx.x;
  int t = threadIdx.x;
  if (b < 256) {
    int rr = b >> 2, qq = b & 3;
    for (int i = 0; i < 8; ++i) {
      int idx = qq * 2048 + i * 256 + t;   // (x,h)
      int x = idx >> 7, h = idx & 127;
      float val = w2[((size_t)x * RD + rr) * HD + h];
      __hip_bfloat16 hv = __float2bfloat16(val);
      w2t[((size_t)rr * XD + x) * HD + h] = *(u16*)&hv;
    }
  } else if (b < 384) {
    int bb = b - 256;
    int n = bb >> 4, sb = (bb & 15) * 64;
    for (int i = 0; i < 4; ++i) {
      int flat = i * 256 + t;
      int s = flat >> 4, ch = flat & 15;
      f32x4 d = *(const f32x4*)(r + ((size_t)(n * SITES + sb + s) * RD + ch * 4));
      *(f32x4*)&tl[s][ch * 4] = d;
    }
    __syncthreads();
    for (int i = 0; i < 4; ++i) {
      int flat = i * 256 + t;
      int rr = flat >> 4, ch = flat & 15;
      f32x4 o;
      o.x = tl[ch * 4 + 0][rr];
      o.y = tl[ch * 4 + 1][rr];
      o.z = tl[ch * 4 + 2][rr];
      o.w = tl[ch * 4 + 3][rr];
      *(f32x4*)(rt + ((size_t)(n * RD + rr) * SITES + sb + ch * 4)) = o;
    }
  } else {
    int f = (b - 384) * 256 + t;        // 524288 f32x4 units of ut
    int nh = f & 1, v = (f >> 1) & 63, uu = (f >> 7) & 63, rr = f >> 13;
    f32x4 o;
#pragma unroll
    for (int k = 0; k < 4; ++k)
      o[k] = u[(((size_t)(nh * 4 + k) * RD + rr) * UD + uu) * VD + v];
    *(f32x4*)(ut + (size_t)f * 4) = o;
  }
}

// ---------------- k_a_full v3: u-split, zero-redundancy, 16 waves/CU ------------
// R2 post-mortem: the n-group split made 4 wave-groups read the SAME w1 bytes;
// wave drift defeated L1/L2 absorption -> FETCH 282 MB (2.1x) at 2.9 TB/s.
// v3 splits along u instead (redundancy-free: every w1/ut byte read once
// grid-wide), keeps 16 waves/CU (512 blocks x 512 thr, 2 blocks/CU).
// Each thread: all 8 n, 4 h, 1 v, HALF the u range (32).  LDS reduce adds the
// two u-halves (same u0..31 + u32..63 order as the R0 part[0]+part[1] path),
// then the proven transpose epilogue emits bf16 at[n][r][h][v].
#define PF 4
__global__ __launch_bounds__(512, 4) void k_a_full(const float* __restrict__ w1,
                                                   const float* __restrict__ ut,
                                                   u16* __restrict__ at) {
  __shared__ float red[256 * 32];       // 32 KB: [L][slot^swz][j] uh=1 partials
  __shared__ float tile[8 * 32 * 33];   // 33 KB: [n][h_local][v_local] transposed
  int b = blockIdx.x;                   // 512 = rr(64) x vh(2) x hb(4)
  int rr = b >> 3, vh = (b >> 2) & 1, hb = b & 3;
  int t = threadIdx.x;
  int uh = t >> 8;                      // u-half: uu in [uh*32, uh*32+32)
  int L = t & 255;
  int vl = L >> 3, hs = L & 7;          // v-local (32), h-strip (8 strips x 4 h)
  int v = vh * 32 + vl;
  int h0 = hb * 32 + hs * 4;
  const float* w1p = w1 + (((size_t)(rr * UD + uh * 32)) * VD + v) * HD + h0;
  const float* up  = ut + (((size_t)(rr * UD + uh * 32)) * VD + v) * NB;
  const size_t wstep = (size_t)VD * HD;   // floats per uu in w1
  const size_t ustep = (size_t)VD * NB;   // floats per uu in ut

  f32x4 acc[8];
#pragma unroll
  for (int n = 0; n < 8; ++n) acc[n] = (f32x4)0.f;

  // PF=4 prefetch ring, fully-unrolled loop -> static indices (rule #20 safe)
  f32x4 wa[PF], ua[PF], ub[PF];
#pragma unroll
  for (int p = 0; p < PF; ++p) {
    wa[p] = *(const f32x4*)(w1p + (size_t)p * wstep);
    ua[p] = *(const f32x4*)(up + (size_t)p * ustep);
    ub[p] = *(const f32x4*)(up + (size_t)p * ustep + 4);
  }
#pragma unroll
  for (int uu = 0; uu < 32; ++uu) {
    const int p = uu & (PF - 1);
    f32x4 wv = wa[p];
    f32x4 a0 = ua[p];
    f32x4 a1 = ub[p];
    if (uu + PF < 32) {
      wa[p] = *(const f32x4*)(w1p + (size_t)(uu + PF) * wstep);
      ua[p] = *(const f32x4*)(up + (size_t)(uu + PF) * ustep);
      ub[p] = *(const f32x4*)(up + (size_t)(uu + PF) * ustep + 4);
    }
    acc[0] += wv * a0.x;
    acc[1] += wv * a0.y;
    acc[2] += wv * a0.z;
    acc[3] += wv * a0.w;
    acc[4] += wv * a1.x;
    acc[5] += wv * a1.y;
    acc[6] += wv * a1.z;
    acc[7] += wv * a1.w;
  }

  // ---- reduce the two u-halves: uh=1 stages to LDS, uh=0 adds ----
  // slot swizzle (n ^ (L&7)) spreads the 128 B row stride across banks.
  if (uh == 1) {
#pragma unroll
    for (int n = 0; n < 8; ++n)
      *(f32x4*)&red[L * 32 + ((n ^ (L & 7)) << 2)] = acc[n];
  }
  __syncthreads();
  if (uh == 0) {
#pragma unroll
    for (int n = 0; n < 8; ++n)
      acc[n] += *(const f32x4*)&red[L * 32 + ((n ^ (L & 7)) << 2)];
    // transposed scatter into tile[n][h_local][v_local] (stride 33 breaks banks)
#pragma unroll
    for (int n = 0; n < 8; ++n)
#pragma unroll
      for (int j = 0; j < 4; ++j)
        tile[(n * 32 + hs * 4 + j) * 33 + vl] = acc[n][j];
  }
  __syncthreads();

  // ---- coalesced bf16 store: 2048 u16x4 units, 4 per thread ----
#pragma unroll
  for (int k = 0; k < 4; ++k) {
    int flat = k * 512 + t;
    int vs = flat & 7, hl = (flat >> 3) & 31, n = flat >> 8;
    f32x4 blk = *(const f32x4*)&tile[(n * 32 + hl) * 33 + vs * 4];
    u16x4 o;
#pragma unroll
    for (int j = 0; j < 4; ++j) {
      __hip_bfloat16 hv = __float2bfloat16(blk[j]);
      o[j] = *(u16*)&hv;
    }
    *(u16x4*)(at + ((size_t)(n * RD + rr) * HD + hb * 32 + hl) * VD + vh * 32 + vs * 4) = o;
  }
}

// ---------------- k_main: fused GEMM1 (P^T = A_r^T * V^T) + relu*r + GEMM2 ------
// R6 known-good structure (512 blocks x 256 thr, 64 KB double-buffered swizzled
// Plds, ONE lds_barrier per rr).  Unchanged.
__global__ __launch_bounds__(256, 1) void k_main(const float* __restrict__ vin,
                                                 const u16* __restrict__ at,
                                                 const u16* __restrict__ w2t,
                                                 const float* __restrict__ rt,
                                                 float* __restrict__ pbuf) {
  __shared__ __align__(16) char Plds[2 * 128 * 256];   // 64 KB exactly
  int b = blockIdx.x;                 // 512 = n(8) x stile(8) x rchunk(8)
  int rc = b & 7, st = (b >> 3) & 7, n = b >> 6;
  int t = threadIdx.x;
  int w = t >> 6, L = t & 63, q = L >> 4, c = L & 15;
  int g2m = w >> 1, g2x = w & 1;      // GEMM2: s-half x x-half

  // V fragments (B-operand of GEMM1), register-resident for all r-steps
  bf16x8 vf[4][2];
#pragma unroll
  for (int nt = 0; nt < 4; ++nt)
#pragma unroll
    for (int ks = 0; ks < 2; ++ks) {
      int s = (w & 1) * 64 + nt * 16 + c;
      const float* vp = vin + ((size_t)(n * SITES + st * 128 + s) * VD + ks * 32 + q * 8);
      f32x4 a0 = *(const f32x4*)vp;
      f32x4 a1 = *(const f32x4*)(vp + 4);
      bf16x8 f;
      f[0] = (__bf16)a0.x; f[1] = (__bf16)a0.y; f[2] = (__bf16)a0.z; f[3] = (__bf16)a0.w;
      f[4] = (__bf16)a1.x; f[5] = (__bf16)a1.y; f[6] = (__bf16)a1.z; f[7] = (__bf16)a1.w;
      vf[nt][ks] = f;
    }

  f32x4 o[4][2];
#pragma unroll
  for (int i = 0; i < 4; i++)
#pragma unroll
    for (int j = 0; j < 2; j++) o[i][j] = (f32x4)0.f;

  int g1m = w >> 1, g1n = w & 1;      // GEMM1: h-half x s-half
  for (int rr = rc * 8; rr < rc * 8 + 8; ++rr) {
    const u16* abase = at + (size_t)(n * RD + rr) * 8192;   // [h][v] plain

    // A-frags direct from global: 16B = 8 consecutive v at fixed h
    bf16x8 af[4][2];
#pragma unroll
    for (int mt = 0; mt < 4; ++mt)
#pragma unroll
      for (int ks = 0; ks < 2; ++ks) {
        int h = g1m * 64 + mt * 16 + c;
        int vb = ks * 4 + q;
        af[mt][ks] = *(const bf16x8*)(abase + (size_t)h * VD + vb * 8);
      }
    // W2r b-frags from global (L2-hot)
    u32x4 wraw[2][4];
#pragma unroll
    for (int xt = 0; xt < 2; ++xt)
#pragma unroll
      for (int k2 = 0; k2 < 4; ++k2) {
        int xg = g2x * 32 + xt * 16 + c;
        wraw[xt][k2] = *(const u32x4*)((const char*)w2t +
                        (((size_t)(rr * XD + xg)) * HD + k2 * 32 + q * 8) * 2);
      }
    float rsc[4];
#pragma unroll
    for (int nt = 0; nt < 4; ++nt)
      rsc[nt] = rt[(size_t)(n * RD + rr) * SITES + st * 128 + g1n * 64 + nt * 16 + c];

    // GEMM1: D = A_r^T (m=h) x V^T (n=s), K=v=64
    f32x4 cc[4][4];
#pragma unroll
    for (int mt = 0; mt < 4; ++mt)
#pragma unroll
      for (int nt = 0; nt < 4; ++nt) cc[mt][nt] = (f32x4)0.f;
#pragma unroll
    for (int ks = 0; ks < 2; ++ks)
#pragma unroll
      for (int mt = 0; mt < 4; ++mt)
#pragma unroll
        for (int nt = 0; nt < 4; ++nt)
          cc[mt][nt] = __builtin_amdgcn_mfma_f32_16x16x32_bf16(af[mt][ks], vf[nt][ks],
                                                               cc[mt][nt], 0, 0, 0);

    // relu, scale by r, pack to Plds buf rr&1, XOR-swizzled 16B blocks:
    // element (s, h-block hb8=h>>3) stored at block (hb8 ^ (s&15)) within row s.
    char* PB = Plds + (rr & 1) * 32768;
#pragma unroll
    for (int mt = 0; mt < 4; ++mt)
#pragma unroll
      for (int nt = 0; nt < 4; ++nt) {
        float sc = rsc[nt];
        bf16x4 pv;
#pragma unroll
        for (int jj = 0; jj < 4; ++jj) {
          float x = cc[mt][nt][jj];
          x = x > 0.f ? x : 0.f;
          pv[jj] = (__bf16)(x * sc);
        }
        int s = g1n * 64 + nt * 16 + c;          // s&15 == c
        int blk = g1m * 8 + mt * 2 + (q >> 1);   // = h>>3
        *(bf16x4*)(PB + (size_t)s * 256 + (size_t)((blk ^ c) * 16 + (q & 1) * 8)) = pv;
      }
    lds_barrier();   // lgkm-only barrier — no vmcnt(0) drain per rr

    // GEMM2: O[s,x] += P (m=s, A-op) x W2r^T (n=x), K=h=128
#pragma unroll
    for (int k2 = 0; k2 < 4; ++k2) {
      bf16x8 wf0 = __builtin_bit_cast(bf16x8, wraw[0][k2]);
      bf16x8 wf1 = __builtin_bit_cast(bf16x8, wraw[1][k2]);
#pragma unroll
      for (int mt = 0; mt < 4; ++mt) {
        int s = g2m * 64 + mt * 16 + c;          // s&15 == c
        int blk = k2 * 4 + q;                    // = h>>3
        bf16x8 pf = *(const bf16x8*)(PB + (size_t)s * 256 + (size_t)((blk ^ c) * 16));
        o[mt][0] = __builtin_amdgcn_mfma_f32_16x16x32_bf16(pf, wf0, o[mt][0], 0, 0, 0);
        o[mt][1] = __builtin_amdgcn_mfma_f32_16x16x32_bf16(pf, wf1, o[mt][1], 0, 0, 0);
      }
    }
  }
  // epilogue: plain vector stores to partial buffer pbuf[rc][n][st][x][s]
#pragma unroll
  for (int mt = 0; mt < 4; ++mt)
#pragma unroll
    for (int xt = 0; xt < 2; ++xt) {
      int s0 = g2m * 64 + mt * 16 + q * 4;
      int x = g2x * 32 + xt * 16 + c;
      size_t off = ((((size_t)rc * NB + n) * 8 + st) * XD + x) * 128 + s0;
      *(f32x4*)(pbuf + off) = o[mt][xt];
    }
}

// ---------------- k_reduce: out[n][s][x] = sum_rc pbuf[rc][n][st][x][s] ---------
__global__ __launch_bounds__(256) void k_reduce(const float* __restrict__ pbuf,
                                                float* __restrict__ out) {
  __shared__ float tile[128][17];
  int b = blockIdx.x;                 // 256 = n(8) x st(8) x xq(4)
  int n = b >> 5, st = (b >> 2) & 7, xq = b & 3;
  int t = threadIdx.x;
  int sq = t & 31, xl = t >> 5;       // phase-1: s-quad, x-lane (8)
#pragma unroll
  for (int p = 0; p < 2; ++p) {
    int x = xq * 16 + p * 8 + xl;
    f32x4 sum = (f32x4)0.f;
#pragma unroll
    for (int rcc = 0; rcc < 8; ++rcc) {
      size_t off = ((((size_t)rcc * NB + n) * 8 + st) * XD + x) * 128 + sq * 4;
      f32x4 d = *(const f32x4*)(pbuf + off);
      sum.x += d.x; sum.y += d.y; sum.z += d.z; sum.w += d.w;
    }
#pragma unroll
    for (int k = 0; k < 4; ++k) tile[sq * 4 + k][p * 8 + xl] = sum[k];
  }
  __syncthreads();
  // phase-2: coalesced out write, f32x4 along x
#pragma unroll
  for (int k = 0; k < 2; ++k) {
    int flat = k * 256 + t;
    int s = flat >> 2, c4 = flat & 3;
    f32x4 o;
#pragma unroll
    for (int j = 0; j < 4; ++j) o[j] = tile[s][c4 * 4 + j];
    *(f32x4*)(out + ((size_t)(n * SITES + st * 128 + s) * XD + xq * 16 + c4 * 4)) = o;
  }
}

extern "C" void kernel_launch(void* const* d_in, const int* in_sizes, int n_in,
                              void* d_out, int out_size, void* d_ws, size_t ws_size,
                              hipStream_t stream) {
  const float* r  = (const float*)d_in[0];
  const float* u  = (const float*)d_in[1];
  const float* v  = (const float*)d_in[2];
  const float* w1 = (const float*)d_in[3];
  const float* w2 = (const float*)d_in[4];
  float* out = (float*)d_out;
  char* ws = (char*)d_ws;
  u16* at     = (u16*)(ws);                         // 8 MB  bf16 a, [n][r][h][v]
  u16* w2t    = (u16*)(ws + ((size_t)8 << 20));     // 1 MB  bf16 w2 [r][x][h]
  float* rt   = (float*)(ws + ((size_t)9 << 20));   // 2 MB  fp32 r [n][r][s]
  float* ut   = (float*)(ws + ((size_t)11 << 20));  // 8 MB  fp32 u [r][u][v][n]
  float* pbuf = (float*)(ws + ((size_t)19 << 20));  // 16 MB fp32 out-partials [rc][n][st][x][s]

  hipLaunchKernelGGL(kprep, dim3(2432), dim3(256), 0, stream, w2, w2t, r, rt, u, ut);
  hipLaunchKernelGGL(k_a_full, dim3(512), dim3(512), 0, stream, w1, ut, at);
  hipLaunchKernelGGL(k_main, dim3(512), dim3(256), 0, stream, v, at, w2t, rt, pbuf);
  hipLaunchKernelGGL(k_reduce, dim3(256), dim3(256), 0, stream, pbuf, out);
}